// Round 1
// baseline (70.226 us; speedup 1.0000x reference)
//
#include <hip/hip_runtime.h>
#include <hip/hip_bf16.h>

// B=4, S=512, H=128
// out[b,i,h] = tanh( (1/L_b) * sum_j m_i*m_j * inp[b,j,h] * sigmoid(g0[b,i,h]+g1[b,j,h]) )
// g0 = inp @ W0^T + b0 ; g1 = inp @ W1^T + b1
//
// Trick: sigmoid(a+b) = E0*E1 / (1 + E0*E1), E0=exp(g0), E1=exp(g1) precomputed.
// Masks are 0/1 -> compact valid indices, skip masked i and j entirely.

#define BB 4
#define SS 512
#define HH 128

// ---------------- kernel 0: mask compaction ----------------
// one block, 256 threads = 4 waves; wave w handles batch b=w
__global__ __launch_bounds__(256) void k0_compact(const int* __restrict__ masks,
                                                  int* __restrict__ valid_idx,
                                                  int* __restrict__ nvalid,
                                                  float* __restrict__ rcpL) {
    int wave = threadIdx.x >> 6;
    int lane = threadIdx.x & 63;
    if (wave >= BB) return;
    int b = wave;
    int base = 0;
    for (int c = 0; c < SS; c += 64) {
        int j = c + lane;
        int m = masks[b * SS + j];
        unsigned long long bits = __ballot(m != 0);
        int pos = __popcll(bits & ((1ull << lane) - 1ull));
        if (m) valid_idx[b * SS + base + pos] = j;
        base += __popcll(bits);
    }
    if (lane == 0) {
        nvalid[b] = base;
        rcpL[b] = base ? (1.0f / (float)base) : 0.0f;
    }
}

// ---------------- kernel 1: gates + exp ----------------
// grid: (B*S/R) blocks, 256 threads: (o = tid&127, g = tid>>7)
// Each block computes R=8 rows of both gates; E_g[row][o] = exp(gate).
// Also zeroes out[] for masked rows (those are skipped by k2).
#define R1 8
__global__ __launch_bounds__(256) void k1_gates(const float* __restrict__ inp,
                                                const int* __restrict__ masks,
                                                const float* __restrict__ W0,
                                                const float* __restrict__ b0,
                                                const float* __restrict__ W1,
                                                const float* __restrict__ b1,
                                                float* __restrict__ E0,
                                                float* __restrict__ E1,
                                                float* __restrict__ out) {
    __shared__ float s_inp[R1][HH];
    const int row0 = blockIdx.x * R1;
    const int tid = threadIdx.x;

    // stage R1 rows of inp: R1*128 = 1024 floats = 256 float4
    {
        const float4* src = (const float4*)(inp + (size_t)row0 * HH);
        float4* dst = (float4*)&s_inp[0][0];
        dst[tid] = src[tid];
    }
    __syncthreads();

    const int o = tid & 127;
    const int g = tid >> 7;
    const float* __restrict__ W = g ? W1 : W0;
    const float bias = g ? b1[o] : b0[o];

    float acc[R1];
#pragma unroll
    for (int r = 0; r < R1; ++r) acc[r] = bias;

    const float* __restrict__ Wrow = W + (size_t)o * HH;
    for (int k = 0; k < HH; k += 4) {
        float4 w4 = *(const float4*)(Wrow + k);
#pragma unroll
        for (int r = 0; r < R1; ++r) {
            float4 x4 = *(const float4*)&s_inp[r][k];
            float a = acc[r];
            a = fmaf(x4.x, w4.x, a);
            a = fmaf(x4.y, w4.y, a);
            a = fmaf(x4.z, w4.z, a);
            a = fmaf(x4.w, w4.w, a);
            acc[r] = a;
        }
    }

    float* __restrict__ E = g ? E1 : E0;
#pragma unroll
    for (int r = 0; r < R1; ++r)
        E[(size_t)(row0 + r) * HH + o] = __builtin_amdgcn_exp2f(acc[r] * 1.44269504088896f);

    // zero output rows where mask==0 (half g==0 does it)
    if (g == 0) {
#pragma unroll
        for (int r = 0; r < R1; ++r)
            if (masks[row0 + r] == 0) out[(size_t)(row0 + r) * HH + o] = 0.0f;
    }
}

// ---------------- kernel 2: main pairwise loop ----------------
// grid: B * (S/4) blocks, 256 threads: h = tid&127, half = tid>>7.
// Block (b,q) handles valid i's at positions [4q, 4q+4) of valid_idx[b];
// each thread-half owns 2 of them (2 accumulators, loads amortized x2).
__global__ __launch_bounds__(256) void k2_main(const float* __restrict__ inp,
                                               const float* __restrict__ E0,
                                               const float* __restrict__ E1,
                                               const int* __restrict__ valid_idx,
                                               const int* __restrict__ nvalid,
                                               const float* __restrict__ rcpL,
                                               float* __restrict__ out) {
    const int b = blockIdx.x >> 7;        // 128 blocks per batch (S/4)
    const int q = blockIdx.x & 127;
    const int nv = nvalid[b];
    const int p = q * 4;
    if (p >= nv) return;

    const int h = threadIdx.x & 127;
    const int half = threadIdx.x >> 7;

    const int* __restrict__ vj = valid_idx + b * SS;
    const int ia = p + 2 * half;
    const int ib = ia + 1;
    const bool va = ia < nv;
    const bool vb = ib < nv;
    const int i0 = vj[va ? ia : 0];
    const int i1 = vj[vb ? ib : 0];

    const size_t boff = (size_t)b * SS * HH;
    const float* __restrict__ E0b = E0 + boff;
    const float* __restrict__ E1b = E1 + boff;
    const float* __restrict__ inb = inp + boff;

    // e0 = 0 for invalid slots -> sigmoid term = 0 -> no contribution
    const float e00 = va ? E0b[(size_t)i0 * HH + h] : 0.0f;
    const float e01 = vb ? E0b[(size_t)i1 * HH + h] : 0.0f;

    float a0 = 0.0f, a1 = 0.0f;
#pragma unroll 2
    for (int t = 0; t < nv; ++t) {
        const int j = vj[t];
        const float e1 = E1b[(size_t)j * HH + h];
        const float x = inb[(size_t)j * HH + h];
        const float t0 = e00 * e1;
        const float t1 = e01 * e1;
        a0 = fmaf(x * t0, __builtin_amdgcn_rcpf(1.0f + t0), a0);
        a1 = fmaf(x * t1, __builtin_amdgcn_rcpf(1.0f + t1), a1);
    }

    const float rl = rcpL[b];
    if (va) out[boff + (size_t)i0 * HH + h] = tanhf(a0 * rl);
    if (vb) out[boff + (size_t)i1 * HH + h] = tanhf(a1 * rl);
}

extern "C" void kernel_launch(void* const* d_in, const int* in_sizes, int n_in,
                              void* d_out, int out_size, void* d_ws, size_t ws_size,
                              hipStream_t stream) {
    const float* inp = (const float*)d_in[0];
    const int* masks = (const int*)d_in[1];
    const float* W0 = (const float*)d_in[2];
    const float* b0 = (const float*)d_in[3];
    const float* W1 = (const float*)d_in[4];
    const float* b1 = (const float*)d_in[5];
    float* out = (float*)d_out;

    // workspace layout
    const size_t nBSH = (size_t)BB * SS * HH;          // 262144
    float* E0 = (float*)d_ws;                          // 1 MB
    float* E1 = E0 + nBSH;                             // 1 MB
    int* valid_idx = (int*)(E1 + nBSH);                // 8 KB
    int* nvalid = valid_idx + BB * SS;                 // 16 B
    float* rcpL = (float*)(nvalid + BB);               // 16 B

    k0_compact<<<1, 256, 0, stream>>>(masks, valid_idx, nvalid, rcpL);
    k1_gates<<<(BB * SS) / R1, 256, 0, stream>>>(inp, masks, W0, b0, W1, b1, E0, E1, out);
    k2_main<<<BB * (SS / 4), 256, 0, stream>>>(inp, E0, E1, valid_idx, nvalid, rcpL, out);
}

// Round 2
// 37.165 us; speedup vs baseline: 1.8896x; 1.8896x over previous
//
#include <hip/hip_runtime.h>
#include <hip/hip_bf16.h>

// B=4, S=512, H=128
// out[b,i,h] = tanh( (1/L_b) * sum_j m_i*m_j * inp[b,j,h] * sigmoid(g0[b,i,h]+g1[b,j,h]) )
// sigmoid(a+b) = t/(1+t), t = E0*E1, E0=exp(g0), E1=exp(g1).
// x*sigma = x - x/(1+t)  -> share sum(x) across the 4 i-chains per thread.

#define BB 4
#define SS 512
#define HH 128

// ---------------- kernel 0: mask compaction ----------------
__global__ __launch_bounds__(256) void k0_compact(const int* __restrict__ masks,
                                                  int* __restrict__ valid_idx,
                                                  int* __restrict__ nvalid,
                                                  float* __restrict__ rcpL) {
    int wave = threadIdx.x >> 6;
    int lane = threadIdx.x & 63;
    if (wave >= BB) return;
    int b = wave;
    int base = 0;
    for (int c = 0; c < SS; c += 64) {
        int j = c + lane;
        int m = masks[b * SS + j];
        unsigned long long bits = __ballot(m != 0);
        int pos = __popcll(bits & ((1ull << lane) - 1ull));
        if (m) valid_idx[b * SS + base + pos] = j;
        base += __popcll(bits);
    }
    if (lane == 0) {
        nvalid[b] = base;
        rcpL[b] = base ? (1.0f / (float)base) : 0.0f;
    }
}

// ---------------- kernel 1: gates + exp ----------------
// grid: B*S/R1 blocks, 256 threads (o = tid&127, g = tid>>7). R1=4 rows/block.
#define R1 4
__global__ __launch_bounds__(256) void k1_gates(const float* __restrict__ inp,
                                                const int* __restrict__ masks,
                                                const float* __restrict__ W0,
                                                const float* __restrict__ b0,
                                                const float* __restrict__ W1,
                                                const float* __restrict__ b1,
                                                float* __restrict__ E0,
                                                float* __restrict__ E1,
                                                float* __restrict__ out) {
    __shared__ float s_inp[R1][HH];
    const int row0 = blockIdx.x * R1;
    const int tid = threadIdx.x;

    // stage R1 rows of inp: R1*128 = 512 floats = 128 float4
    if (tid < 128) {
        const float4* src = (const float4*)(inp + (size_t)row0 * HH);
        float4* dst = (float4*)&s_inp[0][0];
        dst[tid] = src[tid];
    }
    __syncthreads();

    const int o = tid & 127;
    const int g = tid >> 7;
    const float* __restrict__ W = g ? W1 : W0;
    const float bias = g ? b1[o] : b0[o];

    float acc[R1];
#pragma unroll
    for (int r = 0; r < R1; ++r) acc[r] = bias;

    const float* __restrict__ Wrow = W + (size_t)o * HH;
#pragma unroll 4
    for (int k = 0; k < HH; k += 4) {
        float4 w4 = *(const float4*)(Wrow + k);
#pragma unroll
        for (int r = 0; r < R1; ++r) {
            float4 x4 = *(const float4*)&s_inp[r][k];
            float a = acc[r];
            a = fmaf(x4.x, w4.x, a);
            a = fmaf(x4.y, w4.y, a);
            a = fmaf(x4.z, w4.z, a);
            a = fmaf(x4.w, w4.w, a);
            acc[r] = a;
        }
    }

    float* __restrict__ E = g ? E1 : E0;
#pragma unroll
    for (int r = 0; r < R1; ++r)
        E[(size_t)(row0 + r) * HH + o] = __builtin_amdgcn_exp2f(acc[r] * 1.44269504088896f);

    // zero output rows where mask==0 (k2/k3 skip them)
    if (g == 0) {
#pragma unroll
        for (int r = 0; r < R1; ++r)
            if (masks[row0 + r] == 0) out[(size_t)(row0 + r) * HH + o] = 0.0f;
    }
}

// ---------------- kernel 2: pairwise partial sums ----------------
// grid: B * (SS/4) * js blocks, 128 threads (h = tid).
// Block = (b, qi, jc): 4 valid-i positions [4qi,4qi+4), j-chunk jc of js.
// partial layout: [(b*js + jc)][p][h], p = position in valid list.
__global__ __launch_bounds__(128) void k2_main(const float* __restrict__ inp,
                                               const float* __restrict__ E0,
                                               const float* __restrict__ E1,
                                               const int* __restrict__ valid_idx,
                                               const int* __restrict__ nvalid,
                                               float* __restrict__ partial,
                                               int js) {
    const int bid = blockIdx.x;
    const int jc = bid % js;
    const int tmp = bid / js;
    const int qi = tmp & 127;     // SS/4 = 128
    const int b = tmp >> 7;
    const int nv = nvalid[b];
    const int p0 = qi * 4;
    if (p0 >= nv) return;

    const int h = threadIdx.x;
    const int* __restrict__ vj = valid_idx + b * SS;

    const size_t boff = (size_t)b * SS * HH;
    const float* __restrict__ E0b = E0 + boff;
    const float* __restrict__ E1b = E1 + boff;
    const float* __restrict__ inb = inp + boff;

    float e0r[4];
#pragma unroll
    for (int r = 0; r < 4; ++r)
        e0r[r] = (p0 + r < nv) ? E0b[(size_t)vj[p0 + r] * HH + h] : 0.0f;

    const int chunk = (nv + js - 1) / js;
    const int jb = jc * chunk;
    const int je = min(nv, jb + chunk);

    // acc[r] accumulates sum x/(1+t); sumx accumulates sum x.
    // x*sigma = x - x/(1+t). Invalid r slots: e0r=0 -> x/(1+0)=x -> result 0.
    float acc[4] = {0.f, 0.f, 0.f, 0.f};
    float sumx = 0.f;
#pragma unroll 4
    for (int t = jb; t < je; ++t) {
        const int j = vj[t];
        const float e1 = E1b[(size_t)j * HH + h];
        const float x = inb[(size_t)j * HH + h];
        sumx += x;
#pragma unroll
        for (int r = 0; r < 4; ++r) {
            const float t0 = e0r[r] * e1;
            acc[r] = fmaf(x, __builtin_amdgcn_rcpf(1.0f + t0), acc[r]);
        }
    }

    float* __restrict__ pp = partial + ((size_t)(b * js + jc) * SS + p0) * HH + h;
#pragma unroll
    for (int r = 0; r < 4; ++r)
        if (p0 + r < nv) pp[(size_t)r * HH] = sumx - acc[r];
}

// ---------------- kernel 3: reduce partials + tanh ----------------
// grid: B*SS*HH/256 = 1024 blocks.
__global__ __launch_bounds__(256) void k3_finish(const float* __restrict__ partial,
                                                 const int* __restrict__ valid_idx,
                                                 const int* __restrict__ nvalid,
                                                 const float* __restrict__ rcpL,
                                                 float* __restrict__ out,
                                                 int js) {
    const int flat = blockIdx.x * 256 + threadIdx.x;
    const int h = flat & 127;
    const int p = (flat >> 7) & 511;
    const int b = flat >> 16;
    if (p >= nvalid[b]) return;

    const float* __restrict__ pp = partial + ((size_t)(b * js) * SS + p) * HH + h;
    float s = 0.f;
    for (int jc = 0; jc < js; ++jc) s += pp[(size_t)jc * SS * HH];

    float x = s * rcpL[b];
    x = fminf(fmaxf(x, -30.0f), 30.0f);
    const float e = __builtin_amdgcn_exp2f(x * 2.885390081777927f); // exp(2x)
    const float th = (e - 1.0f) * __builtin_amdgcn_rcpf(e + 1.0f);
    const int i = valid_idx[b * SS + p];
    out[((size_t)b * SS + i) * HH + h] = th;
}

extern "C" void kernel_launch(void* const* d_in, const int* in_sizes, int n_in,
                              void* d_out, int out_size, void* d_ws, size_t ws_size,
                              hipStream_t stream) {
    const float* inp = (const float*)d_in[0];
    const int* masks = (const int*)d_in[1];
    const float* W0 = (const float*)d_in[2];
    const float* b0 = (const float*)d_in[3];
    const float* W1 = (const float*)d_in[4];
    const float* b1 = (const float*)d_in[5];
    float* out = (float*)d_out;

    const size_t nBSH = (size_t)BB * SS * HH; // 262144
    float* E0 = (float*)d_ws;                 // 1 MB
    float* E1 = E0 + nBSH;                    // 1 MB
    int* valid_idx = (int*)(E1 + nBSH);       // 8 KB
    int* nvalid = valid_idx + BB * SS;
    float* rcpL = (float*)(nvalid + BB);
    float* partial = rcpL + BB;               // js * 1 MB

    const size_t fixed_bytes = (size_t)((char*)partial - (char*)d_ws);
    int js = 8;
    while (js > 1 && fixed_bytes + (size_t)js * nBSH * sizeof(float) > ws_size)
        js >>= 1;

    k0_compact<<<1, 256, 0, stream>>>(masks, valid_idx, nvalid, rcpL);
    k1_gates<<<(BB * SS) / R1, 256, 0, stream>>>(inp, masks, W0, b0, W1, b1, E0, E1, out);
    k2_main<<<BB * (SS / 4) * js, 128, 0, stream>>>(inp, E0, E1, valid_idx, nvalid, partial, js);
    k3_finish<<<(BB * SS * HH) / 256, 256, 0, stream>>>(partial, valid_idx, nvalid, rcpL, out, js);
}

// Round 3
// 28.023 us; speedup vs baseline: 2.5060x; 1.3263x over previous
//
#include <hip/hip_runtime.h>
#include <hip/hip_bf16.h>

// B=4, S=512, H=128
// out[b,i,h] = tanh( (1/L_b) * sum_j m_i*m_j * inp[b,j,h] * sigmoid(g0[b,i,h]+g1[b,j,h]) )
// sigmoid = t/(1+t), t = E0*E1;  x*sigma = x - x/(1+t)  (share sum x across i-chains)

#define BB 4
#define SS 512
#define HH 128
#define R1 4

// ---------------- kernel A: gates + exp + pack + compaction ----------------
// grid: BB*SS/R1 + 1 = 513 blocks, 256 threads.
// blocks 0..511: compute R1 rows of both gates; write E0[row][o]=exp(g0),
//   XE[row][o]={inp, exp(g1)}; zero out[] for masked rows.
// block 512: mask compaction (one wave per batch).
__global__ __launch_bounds__(256) void kA(const float* __restrict__ inp,
                                          const int* __restrict__ masks,
                                          const float* __restrict__ W0,
                                          const float* __restrict__ b0,
                                          const float* __restrict__ W1,
                                          const float* __restrict__ b1,
                                          float* __restrict__ E0,
                                          float2* __restrict__ XE,
                                          int* __restrict__ valid_idx,
                                          int* __restrict__ nvalid,
                                          float* __restrict__ rcpL,
                                          float* __restrict__ out) {
    if (blockIdx.x == (BB * SS) / R1) {
        int wave = threadIdx.x >> 6, lane = threadIdx.x & 63;
        if (wave >= BB) return;
        int b = wave, base = 0;
        for (int c = 0; c < SS; c += 64) {
            int m = masks[b * SS + c + lane];
            unsigned long long bits = __ballot(m != 0);
            int pos = __popcll(bits & ((1ull << lane) - 1ull));
            if (m) valid_idx[b * SS + base + pos] = c + lane;
            base += __popcll(bits);
        }
        if (lane == 0) {
            nvalid[b] = base;
            rcpL[b] = base ? 1.0f / (float)base : 0.0f;
        }
        return;
    }

    __shared__ float s_inp[R1][HH];
    const int row0 = blockIdx.x * R1;
    const int tid = threadIdx.x;

    if (tid < 128) {
        const float4* src = (const float4*)(inp + (size_t)row0 * HH);
        float4* dst = (float4*)&s_inp[0][0];
        dst[tid] = src[tid];
    }
    __syncthreads();

    const int o = tid & 127;
    const int g = tid >> 7;
    const float* __restrict__ W = g ? W1 : W0;
    const float bias = g ? b1[o] : b0[o];

    float acc[R1];
#pragma unroll
    for (int r = 0; r < R1; ++r) acc[r] = bias;

    const float* __restrict__ Wrow = W + (size_t)o * HH;
#pragma unroll 4
    for (int k = 0; k < HH; k += 4) {
        float4 w4 = *(const float4*)(Wrow + k);
#pragma unroll
        for (int r = 0; r < R1; ++r) {
            float4 x4 = *(const float4*)&s_inp[r][k];
            float a = acc[r];
            a = fmaf(x4.x, w4.x, a);
            a = fmaf(x4.y, w4.y, a);
            a = fmaf(x4.z, w4.z, a);
            a = fmaf(x4.w, w4.w, a);
            acc[r] = a;
        }
    }

    if (g == 0) {
#pragma unroll
        for (int r = 0; r < R1; ++r)
            E0[(size_t)(row0 + r) * HH + o] =
                __builtin_amdgcn_exp2f(acc[r] * 1.44269504088896f);
#pragma unroll
        for (int r = 0; r < R1; ++r)
            if (masks[row0 + r] == 0) out[(size_t)(row0 + r) * HH + o] = 0.0f;
    } else {
#pragma unroll
        for (int r = 0; r < R1; ++r) {
            float e1 = __builtin_amdgcn_exp2f(acc[r] * 1.44269504088896f);
            XE[(size_t)(row0 + r) * HH + o] = make_float2(s_inp[r][o], e1);
        }
    }
}

// ---------------- kernel B: pairwise + in-block reduce + tanh ----------------
// grid: B * (SS/4) = 512 blocks, 1024 threads (8 j-octants x 128 h).
// Block (b,qi): 4 valid-i positions [4qi,4qi+4). Octant oc handles j-chunk oc.
__global__ __launch_bounds__(1024) void kB(const float* __restrict__ E0,
                                           const float2* __restrict__ XE,
                                           const int* __restrict__ valid_idx,
                                           const int* __restrict__ nvalid,
                                           const float* __restrict__ rcpL,
                                           float* __restrict__ out) {
    const int b = blockIdx.x >> 7;     // SS/4 = 128 blocks per batch
    const int qi = blockIdx.x & 127;
    const int nv = nvalid[b];
    const int p0 = qi * 4;
    if (p0 >= nv) return;

    __shared__ float red[8][4][HH];    // 16 KB
    __shared__ int s_vj[SS];           // 2 KB

    const int tid = threadIdx.x;
    const int h = tid & 127;
    const int oc = tid >> 7;           // 0..7

    if (tid < nv) s_vj[tid] = valid_idx[b * SS + tid];
    __syncthreads();

    const size_t boff = (size_t)b * SS * HH;
    const float* __restrict__ E0b = E0 + boff;
    const float2* __restrict__ XEb = XE + boff;

    float e0r[4];
#pragma unroll
    for (int r = 0; r < 4; ++r)
        e0r[r] = (p0 + r < nv) ? E0b[(size_t)s_vj[p0 + r] * HH + h] : 0.0f;

    const int chunk = (nv + 7) >> 3;
    const int jb = oc * chunk;
    const int je = min(nv, jb + chunk);

    float acc[4] = {0.f, 0.f, 0.f, 0.f};
    float sumx = 0.f;
#pragma unroll 4
    for (int t = jb; t < je; ++t) {
        const int j = s_vj[t];
        const float2 v = XEb[(size_t)j * HH + h];  // {x, e1}
        const float x = v.x, e1 = v.y;
        sumx += x;
#pragma unroll
        for (int r = 0; r < 4; ++r) {
            const float t0 = e0r[r] * e1;
            acc[r] = fmaf(x, __builtin_amdgcn_rcpf(1.0f + t0), acc[r]);
        }
    }

#pragma unroll
    for (int r = 0; r < 4; ++r) red[oc][r][h] = sumx - acc[r];
    __syncthreads();

    if (tid < 512) {
        const int r = tid >> 7;
        if (p0 + r < nv) {
            const int hh = tid & 127;
            float s = 0.f;
#pragma unroll
            for (int q = 0; q < 8; ++q) s += red[q][r][hh];
            float x = s * rcpL[b];
            x = fminf(fmaxf(x, -30.0f), 30.0f);
            const float e = __builtin_amdgcn_exp2f(x * 2.885390081777927f); // exp(2x)
            const float th = (e - 1.0f) * __builtin_amdgcn_rcpf(e + 1.0f);
            out[boff + (size_t)s_vj[p0 + r] * HH + hh] = th;
        }
    }
}

extern "C" void kernel_launch(void* const* d_in, const int* in_sizes, int n_in,
                              void* d_out, int out_size, void* d_ws, size_t ws_size,
                              hipStream_t stream) {
    const float* inp = (const float*)d_in[0];
    const int* masks = (const int*)d_in[1];
    const float* W0 = (const float*)d_in[2];
    const float* b0 = (const float*)d_in[3];
    const float* W1 = (const float*)d_in[4];
    const float* b1 = (const float*)d_in[5];
    float* out = (float*)d_out;

    const size_t nBSH = (size_t)BB * SS * HH;  // 262144
    float* E0 = (float*)d_ws;                  // 1 MB
    float2* XE = (float2*)(E0 + nBSH);         // 2 MB
    int* valid_idx = (int*)(XE + nBSH);        // 8 KB
    int* nvalid = valid_idx + BB * SS;
    float* rcpL = (float*)(nvalid + BB);

    kA<<<(BB * SS) / R1 + 1, 256, 0, stream>>>(inp, masks, W0, b0, W1, b1,
                                               E0, XE, valid_idx, nvalid, rcpL, out);
    kB<<<BB * (SS / 4), 1024, 0, stream>>>(E0, XE, valid_idx, nvalid, rcpL, out);
}